// Round 6
// baseline (109.344 us; speedup 1.0000x reference)
//
#include <hip/hip_runtime.h>
#include <math.h>

#define B_   32
#define N_   512
#define W_   256
#define BN_  (B_*N_)        // 16384
#define NBLK_A 2048         // kA: 8 rows/block (4 waves x 2 rows)
#define NBLK_C 128          // adjacency blocks (4 rows each); +1 setup block
#define RHOG   8192         // rho partial groups (one per kA wave)

__device__ __forceinline__ float wave_reduce_sum64(float v) {
#pragma unroll
    for (int m = 32; m >= 1; m >>= 1) v += __shfl_xor(v, m);
    return v;
}

// ---------------------------------------------------------------------------
// Kernel CP: blocks [0,128): graph-learning top-20 adjacency
//            block 128: precompute Γ/β (affine z), gsz, sed, hse
// ---------------------------------------------------------------------------
__global__ __launch_bounds__(256) void kCP(
    const float* __restrict__ se,
    const float* __restrict__ w2, const float* __restrict__ b2,
    const float* __restrict__ w3, const float* __restrict__ b3,
    const float* __restrict__ w5, const float* __restrict__ b5,
    const float* __restrict__ w7, const float* __restrict__ b7,
    const float* __restrict__ enc_w, const float* __restrict__ enc_b,
    const float* __restrict__ g0w, const float* __restrict__ g0s, const float* __restrict__ g0d,
    const float* __restrict__ g1w, const float* __restrict__ g1s, const float* __restrict__ g1d,
    int* __restrict__ adj, float* __restrict__ ws_gam, float* __restrict__ ws_gsz,
    float* __restrict__ ws_sed, float* __restrict__ ws_hse)
{
    if (blockIdx.x == NBLK_C) {
        // ===================== setup block =====================
        __shared__ float gA[4][8];
        const int tid = threadIdx.x;
        if (tid < 64) {
            // Γ[zi][t] (t=0..6 ↔ S,P1,P2,P3,Q1,Q2,Q3), [zi][7] = β[zi]
            const int zi = tid & 7, t = tid >> 3;
            float acc = (t == 7) ? enc_b[zi] : 0.f;
            for (int c = 0; c < 64; ++c) {
                const int ki = c >> 4, ch = c & 15;
                const int k  = (ki == 0) ? 2 : (ki == 1) ? 3 : (ki == 2) ? 5 : 7;
                const int pl = (k - 1) >> 1;
                const float* cw = (ki == 0) ? w2 : (ki == 1) ? w3 : (ki == 2) ? w5 : w7;
                const float* cb = (ki == 0) ? b2 : (ki == 1) ? b3 : (ki == 2) ? b5 : b7;
                float a;
                if (t == 7) a = cb[ch];
                else if (t == 0) { a = 0.f; for (int j = 0; j < k; ++j) a += cw[ch*k+j]; a *= (1.f/(float)W_); }
                else if (t <= 3) { const int j = pl + t;     a = (j < k)  ? -cw[ch*k+j]*(1.f/(float)W_) : 0.f; }
                else             { const int j = pl - (t-3); a = (j >= 0) ? -cw[ch*k+j]*(1.f/(float)W_) : 0.f; }
                acc += a * enc_w[c*8+zi];
            }
            ws_gam[zi*8+t] = acc;
        } else if (tid < 96) {
            // gsz[q][f] = (W_q @ a_q)[f], f<8 (z rows); q = src0,dst0,src1,dst1
            const int q = (tid-64) >> 3, f = (tid-64) & 7;
            const float* gw = (q >> 1) ? g1w : g0w;
            const float* av = (q >> 1) ? ((q&1) ? g1d : g1s) : ((q&1) ? g0d : g0s);
            float v = 0.f;
            for (int d = 0; d < 16; ++d) v += gw[f*16+d] * av[d];
            ws_gsz[q*8+f] = v;
        } else if (tid < 128) {
            // gA[q][f] = (W_q @ a_q)[8+f] (se rows)
            const int q = (tid-96) >> 3, f = (tid-96) & 7;
            const float* gw = (q >> 1) ? g1w : g0w;
            const float* av = (q >> 1) ? ((q&1) ? g1d : g1s) : ((q&1) ? g0d : g0s);
            float v = 0.f;
            for (int d = 0; d < 16; ++d) v += gw[(8+f)*16+d] * av[d];
            gA[q][f] = v;
        }
        __syncthreads();
        // hse[n][dc] = Σ_f se[n][f] * W_head[8+f][dc&15]
        for (int idx = tid; idx < N_*32; idx += 256) {
            const int n = idx >> 5, dc = idx & 31;
            const float* gw = (dc >> 4) ? g1w : g0w;
            const int dd = dc & 15;
            float v = 0.f;
#pragma unroll
            for (int f = 0; f < 8; ++f) v += se[n*8+f] * gw[(8+f)*16+dd];
            ws_hse[idx] = v;
        }
        // sed[n][q] = Σ_f se[n][f] * gA[q][f]
        for (int idx = tid; idx < N_*4; idx += 256) {
            const int n = idx >> 2, q = idx & 3;
            float v = 0.f;
#pragma unroll
            for (int f = 0; f < 8; ++f) v += se[n*8+f] * gA[q][f];
            ws_sed[idx] = v;
        }
        return;
    }

    // ================= adjacency: normalize + top-20 per row =================
    __shared__ float en[N_][9];               // pad: bank-conflict-free
    const int wave = threadIdx.x >> 6;
    const int lane = threadIdx.x & 63;
    for (int rr = threadIdx.x; rr < N_; rr += 256) {
        float v[8]; float ss = 0.f;
#pragma unroll
        for (int e = 0; e < 8; ++e) { v[e] = se[rr * 8 + e]; ss += v[e] * v[e]; }
        const float inv = 1.0f / fmaxf(sqrtf(ss), 1e-12f);
#pragma unroll
        for (int e = 0; e < 8; ++e) en[rr][e] = v[e] * inv;
    }
    __syncthreads();

    const int i = (blockIdx.x << 2) + wave;
    float ei[8];
#pragma unroll
    for (int e = 0; e < 8; ++e) ei[e] = en[i][e];
    float v[8];
#pragma unroll
    for (int q = 0; q < 8; ++q) {
        const int j = (q << 6) + lane;
        float d = 0.f;
#pragma unroll
        for (int e = 0; e < 8; ++e) d += ei[e] * en[j][e];
        v[q] = (j == i) ? -3.4e38f : d * 0.35355339059327373f;  // 1/sqrt(8)
    }
    int cnt = 1;
    if (lane == 0) adj[i * 24 + 1] = i;          // self first
    for (int it = 0; it < 20; ++it) {
        float bv = v[0]; int bq = 0;
#pragma unroll
        for (int q = 1; q < 8; ++q) if (v[q] > bv) { bv = v[q]; bq = q; }
        int bj = (bq << 6) + lane;
#pragma unroll
        for (int m = 32; m >= 1; m >>= 1) {
            const float ov = __shfl_xor(bv, m);
            const int   oj = __shfl_xor(bj, m);
            if (ov > bv || (ov == bv && oj < bj)) { bv = ov; bj = oj; }
        }
        if (bv <= 0.f) break;                     // relu masks the rest
        if (lane == 0) adj[i * 24 + 1 + cnt] = bj;
        cnt++;
        const int wq = bj >> 6, wl = bj & 63;
#pragma unroll
        for (int q = 0; q < 8; ++q) if (q == wq && lane == wl) v[q] = -3.4e38f;
    }
    if (lane == 0) adj[i * 24] = cnt;
}

// ---------------------------------------------------------------------------
// Kernel A: 2 rows per wave. z affine in u=(S,P1..P3,Q1..Q3) via Γ — only
// DS ops are the S-reduce (12/wave) and one LDS z broadcast (5/wave).
// ---------------------------------------------------------------------------
__global__ __launch_bounds__(256, 4) void kA(
    const float* __restrict__ x,
    const float* __restrict__ dec_w, const float* __restrict__ dec_b,
    const float* __restrict__ g0w, const float* __restrict__ g1w,
    const float* __restrict__ ws_gam, const float* __restrict__ ws_gsz,
    const float* __restrict__ ws_sed, const float* __restrict__ ws_hse,
    float* __restrict__ out_recon, float* __restrict__ out_sdev,
    float* __restrict__ ws_h, float* __restrict__ ws_e, float* __restrict__ ws_rho)
{
    __shared__ float lds_z[4][2][8];
    const int wave = threadIdx.x >> 6;
    const int lane = threadIdx.x & 63;
    const int r0 = (blockIdx.x << 3) + (wave << 1);
    const int n0 = r0 & (N_ - 1), n1 = (r0 + 1) & (N_ - 1);

    // ---- row loads (2 streams + 4 broadcast edge loads)
    const float4 xv0 = reinterpret_cast<const float4*>(x)[(size_t)r0 * 64 + lane];
    const float4 xv1 = reinterpret_cast<const float4*>(x)[(size_t)(r0+1) * 64 + lane];
    const float4 ph0 = reinterpret_cast<const float4*>(x)[(size_t)r0 * 64];        // x[r0][0..3]
    const float4 pt0 = reinterpret_cast<const float4*>(x)[(size_t)r0 * 64 + 63];   // x[r0][252..255]
    const float4 ph1 = reinterpret_cast<const float4*>(x)[(size_t)(r0+1) * 64];
    const float4 pt1 = reinterpret_cast<const float4*>(x)[(size_t)(r0+1) * 64 + 63];

    float S0 = xv0.x + xv0.y + xv0.z + xv0.w;
    float S1 = xv1.x + xv1.y + xv1.z + xv1.w;
#pragma unroll
    for (int m = 32; m >= 1; m >>= 1) { S0 += __shfl_xor(S0, m); S1 += __shfl_xor(S1, m); }

    const float P10 = ph0.x, P20 = P10 + ph0.y, P30 = P20 + ph0.z;
    const float Q10 = pt0.w, Q20 = Q10 + pt0.z, Q30 = Q20 + pt0.y;
    const float P11 = ph1.x, P21 = P11 + ph1.y, P31 = P21 + ph1.z;
    const float Q11 = pt1.w, Q21 = Q11 + pt1.z, Q31 = Q21 + pt1.y;

    // ---- z: lanes 0-15 (zi=lane&7, rr=lane>>3) compute one z each, plus stats
    if (lane < 16) {
        const int zi = lane & 7;
        const int rr = lane >> 3;
        const float4 g0 = reinterpret_cast<const float4*>(ws_gam)[zi * 2];      // Γ S,P1,P2,P3
        const float4 g1 = reinterpret_cast<const float4*>(ws_gam)[zi * 2 + 1];  // Γ Q1,Q2,Q3, β
        const float S  = rr ? S1  : S0;
        const float P1 = rr ? P11 : P10, P2 = rr ? P21 : P20, P3 = rr ? P31 : P30;
        const float Q1 = rr ? Q11 : Q10, Q2 = rr ? Q21 : Q20, Q3 = rr ? Q31 : Q30;
        const float zv = g1.w + g0.x*S + g0.y*P1 + g0.z*P2 + g0.w*P3
                              + g1.x*Q1 + g1.y*Q2 + g1.z*Q3;
        lds_z[wave][rr][zi] = zv;
        // stats (all 16 lanes active: shuffles safe)
        const float a = 1.0f / (1.0f + __expf(-zv));
        float sd = fabsf(a - 0.05f);
        sd += __shfl_xor(sd, 1); sd += __shfl_xor(sd, 2); sd += __shfl_xor(sd, 4);
        if (zi == 0) out_sdev[r0 + rr] = sd * 0.125f;
        const float rho = a + __shfl_xor(a, 8);     // row0+row1 per zi
        if (lane < 8) ws_rho[((size_t)(blockIdx.x << 2) + wave) * 8 + lane] = rho;
    }

    // ---- broadcast z to all lanes via LDS (same-wave: compiler inserts lgkmcnt)
    float z0[8], z1[8];
    {
        const float4* zp = reinterpret_cast<const float4*>(&lds_z[wave][0][0]);
        const float4 a = zp[0], b = zp[1], c = zp[2], d = zp[3];
        z0[0]=a.x; z0[1]=a.y; z0[2]=a.z; z0[3]=a.w;
        z0[4]=b.x; z0[5]=b.y; z0[6]=b.z; z0[7]=b.w;
        z1[0]=c.x; z1[1]=c.y; z1[2]=c.z; z1[3]=c.w;
        z1[4]=d.x; z1[5]=d.y; z1[6]=d.z; z1[7]=d.w;
    }

    // ---- recon: dec_w streamed once, applied to both rows
    {
        const float4 db = reinterpret_cast<const float4*>(dec_b)[lane];
        float4 rec0 = db, rec1 = db;
#pragma unroll
        for (int zi = 0; zi < 8; ++zi) {
            const float4 dw = reinterpret_cast<const float4*>(dec_w)[zi * 64 + lane];
            rec0.x += z0[zi]*dw.x; rec0.y += z0[zi]*dw.y; rec0.z += z0[zi]*dw.z; rec0.w += z0[zi]*dw.w;
            rec1.x += z1[zi]*dw.x; rec1.y += z1[zi]*dw.y; rec1.z += z1[zi]*dw.z; rec1.w += z1[zi]*dw.w;
        }
        reinterpret_cast<float4*>(out_recon)[(size_t)r0 * 64 + lane] = rec0;
        reinterpret_cast<float4*>(out_recon)[(size_t)(r0+1) * 64 + lane] = rec1;
    }

    // ---- GAT h (lanes 0-31) and e (lanes 32-39) — no reductions
    if (lane < 32) {
        const float* gw = (lane >> 4) ? g1w : g0w;
        const int dd = lane & 15;
        float gwz[8];
#pragma unroll
        for (int f = 0; f < 8; ++f) gwz[f] = gw[f * 16 + dd];
        float h0 = ws_hse[n0 * 32 + lane];
        float h1 = ws_hse[n1 * 32 + lane];
#pragma unroll
        for (int f = 0; f < 8; ++f) { h0 += z0[f] * gwz[f]; h1 += z1[f] * gwz[f]; }
        ws_h[(size_t)r0 * 32 + lane] = h0;
        ws_h[(size_t)(r0+1) * 32 + lane] = h1;
    } else if (lane < 40) {
        const int q = (lane - 32) & 3;          // src0,dst0,src1,dst1
        const int rr = (lane - 32) >> 2;
        const int nn = rr ? n1 : n0;
        float v = ws_sed[nn * 4 + q];
#pragma unroll
        for (int f = 0; f < 8; ++f) v += (rr ? z1[f] : z0[f]) * ws_gsz[q * 8 + f];
        ws_e[(size_t)(r0 + rr) * 4 + q] = v;
    }
}

// ---------------------------------------------------------------------------
// Kernel D: sparse GAT aggregation (lane-parallel softmax) + proj(ELU) + head
// half-wave (32 lanes) per (b,i) row; 8 rows per 256-thread block.
// Block 0 / wave 0 additionally reduces rho partials -> KL scalar.
// ---------------------------------------------------------------------------
__global__ __launch_bounds__(256) void kD(
    const float* __restrict__ ws_h, const float* __restrict__ ws_e,
    const int* __restrict__ adj,
    const float* __restrict__ proj_w, const float* __restrict__ proj_b,
    const float* __restrict__ head_w, const float* __restrict__ head_b,
    float* __restrict__ out_pred,
    const float* __restrict__ ws_rho, float* __restrict__ out_kl)
{
    const int lane = threadIdx.x & 63;
    const int wave = threadIdx.x >> 6;
    const int half = lane >> 5;
    const int t32 = lane & 31;                // phase1: neighbor slot; phase2: channel d
    const int ri = (wave << 1) + half;
    const int r = (blockIdx.x << 3) + ri;     // (b,i) row
    const int b = r >> 9;
    const int i = r & (N_ - 1);
    const int cnt = adj[i * 24];

    // own-row attention terms (esrc_h0, edst_h0, esrc_h1, edst_h1)
    const float4 er = reinterpret_cast<const float4*>(ws_e)[r];

    // ---- phase 1: lane t owns neighbor t (cnt <= 21)
    const int j = (t32 < cnt) ? adj[i * 24 + 1 + t32] : i;
    const int rj = (b << 9) | j;
    const float4 ejv = reinterpret_cast<const float4*>(ws_e)[rj];
    float e0 = er.x + ejv.y;  e0 = (e0 >= 0.f) ? e0 : 0.2f * e0;
    float e1 = er.z + ejv.w;  e1 = (e1 >= 0.f) ? e1 : 0.2f * e1;
    if (t32 >= cnt) { e0 = -3.4e38f; e1 = -3.4e38f; }
    float m0 = e0, m1 = e1;
#pragma unroll
    for (int m = 16; m >= 1; m >>= 1) {
        m0 = fmaxf(m0, __shfl_xor(m0, m));
        m1 = fmaxf(m1, __shfl_xor(m1, m));
    }
    float w0 = (t32 < cnt) ? __expf(e0 - m0) : 0.f;
    float w1 = (t32 < cnt) ? __expf(e1 - m1) : 0.f;
    float s0 = w0, s1 = w1;
#pragma unroll
    for (int m = 16; m >= 1; m >>= 1) {
        s0 += __shfl_xor(s0, m);
        s1 += __shfl_xor(s1, m);
    }

    // ---- phase 2: channel d = t32; gather h with independent (unrolled) loads.
    // Both weight shuffles execute CONVERGENTLY, then per-lane select (head-
    // divergent shuffle is UB: ds_bpermute from exec-masked-off lane).
    const int d = t32;
    const int head = d >> 4;
    const float sinv = 1.0f / (head ? s1 : s0);
    float acc = 0.f;
#pragma unroll
    for (int t = 0; t < 21; ++t) {
        const float wt0 = __shfl(w0, t, 32);
        const float wt1 = __shfl(w1, t, 32);
        const int   jt  = __shfl(j, t, 32);
        const float wt  = head ? wt1 : wt0;
        acc += wt * ws_h[(size_t)((b << 9) | jt) * 32 + d];
    }
    const float hval = acc * sinv;   // fused GAT output channel d of row r

    // ---- proj + ELU + head (all-to-all via shuffles within the 32-half)
    float f = proj_b[d];
#pragma unroll
    for (int dd = 0; dd < 32; ++dd) {
        const float hv = __shfl(hval, dd, 32);
        f += hv * proj_w[dd * 32 + d];
    }
    f = (f > 0.f) ? f : expm1f(f);
    float p = f * head_w[d];
#pragma unroll
    for (int mm = 16; mm >= 1; mm >>= 1) p += __shfl_xor(p, mm);
    if (d == 0) out_pred[r] = p + head_b[0];

    // ---- KL tail: block 0, wave 0 only (full wave active -> shuffles safe)
    if (blockIdx.x == 0 && threadIdx.x < 64) {
        float t[8] = {0, 0, 0, 0, 0, 0, 0, 0};
        for (int q = (int)threadIdx.x; q < RHOG; q += 64) {
            const float4 a = reinterpret_cast<const float4*>(ws_rho)[q * 2];
            const float4 bb = reinterpret_cast<const float4*>(ws_rho)[q * 2 + 1];
            t[0] += a.x;  t[1] += a.y;  t[2] += a.z;  t[3] += a.w;
            t[4] += bb.x; t[5] += bb.y; t[6] += bb.z; t[7] += bb.w;
        }
#pragma unroll
        for (int zi = 0; zi < 8; ++zi) t[zi] = wave_reduce_sum64(t[zi]);
        if (threadIdx.x == 0) {
            float kl = 0.f;
#pragma unroll
            for (int zi = 0; zi < 8; ++zi) {
                float rh = t[zi] * (1.0f / (float)BN_);
                rh = fminf(fmaxf(rh, 1e-6f), 1.0f - 1e-6f);
                kl += 0.05f * logf(0.05f / rh) + 0.95f * logf(0.95f / (1.0f - rh));
            }
            out_kl[0] = kl;
        }
    }
}

// ---------------------------------------------------------------------------
extern "C" void kernel_launch(void* const* d_in, const int* in_sizes, int n_in,
                              void* d_out, int out_size, void* d_ws, size_t ws_size,
                              hipStream_t stream)
{
    (void)in_sizes; (void)n_in; (void)out_size; (void)ws_size;
    const float* x     = (const float*)d_in[0];
    const float* w2    = (const float*)d_in[1];
    const float* b2    = (const float*)d_in[2];
    const float* w3    = (const float*)d_in[3];
    const float* b3    = (const float*)d_in[4];
    const float* w5    = (const float*)d_in[5];
    const float* b5    = (const float*)d_in[6];
    const float* w7    = (const float*)d_in[7];
    const float* b7    = (const float*)d_in[8];
    const float* enc_w = (const float*)d_in[9];
    const float* enc_b = (const float*)d_in[10];
    const float* dec_w = (const float*)d_in[11];
    const float* dec_b = (const float*)d_in[12];
    const float* se    = (const float*)d_in[13];
    const float* g0w   = (const float*)d_in[14];
    const float* g0s   = (const float*)d_in[15];
    const float* g0d   = (const float*)d_in[16];
    const float* g1w   = (const float*)d_in[17];
    const float* g1s   = (const float*)d_in[18];
    const float* g1d   = (const float*)d_in[19];
    const float* pw    = (const float*)d_in[20];
    const float* pb    = (const float*)d_in[21];
    const float* hw    = (const float*)d_in[22];
    const float* hb    = (const float*)d_in[23];

    float* out       = (float*)d_out;
    float* out_pred  = out;                          // 16384
    float* out_recon = out + 16384;                  // 4194304
    float* out_kl    = out + 16384 + 4194304;        // 1
    float* out_sdev  = out_kl + 1;                   // 16384

    float* ws_h   = (float*)d_ws;                         // BN_*32
    float* ws_e   = ws_h   + (size_t)BN_ * 32;            // BN_*4
    float* ws_rho = ws_e   + (size_t)BN_ * 4;             // RHOG*8
    float* ws_gam = ws_rho + (size_t)RHOG * 8;            // 64
    float* ws_gsz = ws_gam + 64;                          // 32
    float* ws_sed = ws_gsz + 32;                          // N_*4
    float* ws_hse = ws_sed + (size_t)N_ * 4;              // N_*32
    int*   ws_adj = (int*)(ws_hse + (size_t)N_ * 32);     // N_*24 ints

    hipLaunchKernelGGL(kCP, dim3(NBLK_C + 1), dim3(256), 0, stream,
                       se, w2, b2, w3, b3, w5, b5, w7, b7, enc_w, enc_b,
                       g0w, g0s, g0d, g1w, g1s, g1d,
                       ws_adj, ws_gam, ws_gsz, ws_sed, ws_hse);
    hipLaunchKernelGGL(kA, dim3(NBLK_A), dim3(256), 0, stream,
                       x, dec_w, dec_b, g0w, g1w,
                       ws_gam, ws_gsz, ws_sed, ws_hse,
                       out_recon, out_sdev, ws_h, ws_e, ws_rho);
    hipLaunchKernelGGL(kD, dim3(BN_ / 8), dim3(256), 0, stream,
                       ws_h, ws_e, ws_adj, pw, pb, hw, hb, out_pred,
                       ws_rho, out_kl);
}

// Round 7
// 82.019 us; speedup vs baseline: 1.3331x; 1.3331x over previous
//
#include <hip/hip_runtime.h>
#include <math.h>

#define B_   32
#define N_   512
#define W_   256
#define BN_  (B_*N_)        // 16384
#define NBLK_A 2048         // kA: 8 rows/block (4 waves x 2 rows)
#define RHOG   8192         // rho partial groups (one per kA wave)

__device__ __forceinline__ float wave_reduce_sum64(float v) {
#pragma unroll
    for (int m = 32; m >= 1; m >>= 1) v += __shfl_xor(v, m);
    return v;
}

// ---------------------------------------------------------------------------
// Kernel C2: blocks [0,512): rank-based top-20 adjacency, one block per row.
//            block 512: tiny setup (Gamma/beta affine-z, gsz, gA).
// ---------------------------------------------------------------------------
__global__ __launch_bounds__(256) void kC2(
    const float* __restrict__ se,
    const float* __restrict__ w2, const float* __restrict__ b2,
    const float* __restrict__ w3, const float* __restrict__ b3,
    const float* __restrict__ w5, const float* __restrict__ b5,
    const float* __restrict__ w7, const float* __restrict__ b7,
    const float* __restrict__ enc_w, const float* __restrict__ enc_b,
    const float* __restrict__ g0w, const float* __restrict__ g0s, const float* __restrict__ g0d,
    const float* __restrict__ g1w, const float* __restrict__ g1s, const float* __restrict__ g1d,
    int* __restrict__ adj, float* __restrict__ ws_gam, float* __restrict__ ws_gsz,
    float* __restrict__ ws_gA)
{
    __shared__ float en[N_][9];     // padded: conflict-free
    __shared__ float sim[N_];
    __shared__ int   wc[8];

    const int tid = threadIdx.x;

    if (blockIdx.x == N_) {
        // ===================== setup block =====================
        if (tid < 64) {
            // Gamma[zi][t] (t=0..6 <-> S,P1,P2,P3,Q1,Q2,Q3), [zi][7] = beta[zi]
            const int zi = tid & 7, t = tid >> 3;
            float acc = (t == 7) ? enc_b[zi] : 0.f;
#define GAM_KI(KI, KK, CW, CB)                                                  \
            {                                                                   \
                const int k = KK; const int pl = (k - 1) >> 1;                  \
                _Pragma("unroll")                                               \
                for (int ch = 0; ch < 16; ++ch) {                               \
                    const int c = KI * 16 + ch; float a;                        \
                    if (t == 7) a = CB[ch];                                     \
                    else if (t == 0) {                                          \
                        a = 0.f;                                                \
                        _Pragma("unroll")                                       \
                        for (int j = 0; j < k; ++j) a += CW[ch*k+j];            \
                        a *= (1.f/(float)W_);                                   \
                    } else if (t <= 3) {                                        \
                        const int j = pl + t;                                   \
                        a = (j < k) ? -CW[ch*k+j]*(1.f/(float)W_) : 0.f;        \
                    } else {                                                    \
                        const int j = pl - (t - 3);                             \
                        a = (j >= 0) ? -CW[ch*k+j]*(1.f/(float)W_) : 0.f;       \
                    }                                                           \
                    acc += a * enc_w[c*8+zi];                                   \
                }                                                               \
            }
            GAM_KI(0, 2, w2, b2)
            GAM_KI(1, 3, w3, b3)
            GAM_KI(2, 5, w5, b5)
            GAM_KI(3, 7, w7, b7)
#undef GAM_KI
            ws_gam[zi*8+t] = acc;
        } else if (tid < 96) {
            // gsz[q][f] = (W_q @ a_q)[f], f<8 (z rows); q = src0,dst0,src1,dst1
            const int q = (tid-64) >> 3, f = (tid-64) & 7;
            const float* gw = (q >> 1) ? g1w : g0w;
            const float* av = (q >> 1) ? ((q&1) ? g1d : g1s) : ((q&1) ? g0d : g0s);
            float v = 0.f;
#pragma unroll
            for (int d = 0; d < 16; ++d) v += gw[f*16+d] * av[d];
            ws_gsz[q*8+f] = v;
        } else if (tid < 128) {
            // gA[q][f] = (W_q @ a_q)[8+f] (se rows)
            const int q = (tid-96) >> 3, f = (tid-96) & 7;
            const float* gw = (q >> 1) ? g1w : g0w;
            const float* av = (q >> 1) ? ((q&1) ? g1d : g1s) : ((q&1) ? g0d : g0s);
            float v = 0.f;
#pragma unroll
            for (int d = 0; d < 16; ++d) v += gw[(8+f)*16+d] * av[d];
            ws_gA[q*8+f] = v;
        }
        return;
    }

    // ================== rank block: one row i per block ==================
    const int i = blockIdx.x;

    // normalize all 512 rows cooperatively (2 rows/thread)
#pragma unroll
    for (int p = 0; p < 2; ++p) {
        const int rr = tid + p * 256;
        float v[8]; float ss = 0.f;
#pragma unroll
        for (int e = 0; e < 8; ++e) { v[e] = se[rr*8+e]; ss += v[e]*v[e]; }
        const float inv = 1.0f / fmaxf(sqrtf(ss), 1e-12f);
#pragma unroll
        for (int e = 0; e < 8; ++e) en[rr][e] = v[e] * inv;
    }
    __syncthreads();

    // sim row (2 cols/thread)
    float ei[8];
#pragma unroll
    for (int e = 0; e < 8; ++e) ei[e] = en[i][e];
    const int j0 = tid, j1 = tid + 256;
    float s0 = 0.f, s1 = 0.f;
#pragma unroll
    for (int e = 0; e < 8; ++e) { s0 += ei[e]*en[j0][e]; s1 += ei[e]*en[j1][e]; }
    s0 *= 0.35355339059327373f;   // 1/sqrt(8)
    s1 *= 0.35355339059327373f;
    if (j0 == i) s0 = -3.4e38f;
    if (j1 == i) s1 = -3.4e38f;
    sim[j0] = s0; sim[j1] = s1;
    __syncthreads();

    // rank = #{j' : sim[j'] > sim[j]  or  (== and j' < j)}; dense VALU
    int r0 = 0, r1 = 0;
    for (int q = 0; q < N_/4; ++q) {
        const float4 s4 = reinterpret_cast<const float4*>(sim)[q];
        const int jj = q * 4;
#pragma unroll
        for (int u = 0; u < 4; ++u) {
            const float sj = (u==0) ? s4.x : (u==1) ? s4.y : (u==2) ? s4.z : s4.w;
            r0 += (sj > s0 || (sj == s0 && (jj+u) < j0)) ? 1 : 0;
            r1 += (sj > s1 || (sj == s1 && (jj+u) < j1)) ? 1 : 0;
        }
    }
    const bool sel0 = (r0 < 20) && (s0 > 0.f);
    const bool sel1 = (r1 < 20) && (s1 > 0.f);

    // deterministic compaction: ballot + popcount prefix (order-stable)
    const int wave = tid >> 6, lane = tid & 63;
    const unsigned long long m0 = __ballot(sel0);
    const unsigned long long m1 = __ballot(sel1);
    if (lane == 0) { wc[wave] = __popcll(m0); wc[4+wave] = __popcll(m1); }
    __syncthreads();
    int base0 = 1, base1 = 1;   // slot 0 = self
#pragma unroll
    for (int w = 0; w < 4; ++w) base1 += wc[w];
    for (int w = 0; w < 4; ++w) {
        if (w < wave) { base0 += wc[w]; base1 += wc[4+w]; }
    }
    const unsigned long long below = (lane == 0) ? 0ull : (~0ull >> (64 - lane));
    if (sel0) adj[i*24 + 1 + base0 + __popcll(m0 & below)] = j0;
    if (sel1) adj[i*24 + 1 + base1 + __popcll(m1 & below)] = j1;
    if (tid == 0) {
        int cnt = 1;
#pragma unroll
        for (int w = 0; w < 8; ++w) cnt += wc[w];
        adj[i*24] = cnt;
        adj[i*24 + 1] = i;       // self
    }
}

// ---------------------------------------------------------------------------
// Kernel A: 2 rows/wave. z computed affinely (Gamma) by ALL lanes — no LDS
// round-trip, no divergent z-path. hse/sed terms computed inline from se.
// ---------------------------------------------------------------------------
__global__ __launch_bounds__(256) void kA(
    const float* __restrict__ x,
    const float* __restrict__ dec_w, const float* __restrict__ dec_b,
    const float* __restrict__ g0w, const float* __restrict__ g1w,
    const float* __restrict__ se,
    const float* __restrict__ ws_gam, const float* __restrict__ ws_gsz,
    const float* __restrict__ ws_gA,
    float* __restrict__ out_recon, float* __restrict__ out_sdev,
    float* __restrict__ ws_h, float* __restrict__ ws_e, float* __restrict__ ws_rho)
{
    const int wave = threadIdx.x >> 6;
    const int lane = threadIdx.x & 63;
    const int r0 = (blockIdx.x << 3) + (wave << 1);
    const int n0 = r0 & (N_ - 1), n1 = (r0 + 1) & (N_ - 1);

    // ---- row loads
    const float4 xv0 = reinterpret_cast<const float4*>(x)[(size_t)r0 * 64 + lane];
    const float4 xv1 = reinterpret_cast<const float4*>(x)[(size_t)(r0+1) * 64 + lane];
    const float4 ph0 = reinterpret_cast<const float4*>(x)[(size_t)r0 * 64];
    const float4 pt0 = reinterpret_cast<const float4*>(x)[(size_t)r0 * 64 + 63];
    const float4 ph1 = reinterpret_cast<const float4*>(x)[(size_t)(r0+1) * 64];
    const float4 pt1 = reinterpret_cast<const float4*>(x)[(size_t)(r0+1) * 64 + 63];

    float S0 = xv0.x + xv0.y + xv0.z + xv0.w;
    float S1 = xv1.x + xv1.y + xv1.z + xv1.w;
#pragma unroll
    for (int m = 32; m >= 1; m >>= 1) { S0 += __shfl_xor(S0, m); S1 += __shfl_xor(S1, m); }

    const float P10 = ph0.x, P20 = P10 + ph0.y, P30 = P20 + ph0.z;
    const float Q10 = pt0.w, Q20 = Q10 + pt0.z, Q30 = Q20 + pt0.y;
    const float P11 = ph1.x, P21 = P11 + ph1.y, P31 = P21 + ph1.z;
    const float Q11 = pt1.w, Q21 = Q11 + pt1.z, Q31 = Q21 + pt1.y;

    // ---- z: all lanes, affine in u (Gamma is L1-hot: 64 floats)
    float z0[8], z1[8];
#pragma unroll
    for (int zi = 0; zi < 8; ++zi) {
        const float4 g0 = reinterpret_cast<const float4*>(ws_gam)[zi * 2];
        const float4 g1 = reinterpret_cast<const float4*>(ws_gam)[zi * 2 + 1];
        z0[zi] = g1.w + g0.x*S0 + g0.y*P10 + g0.z*P20 + g0.w*P30
                       + g1.x*Q10 + g1.y*Q20 + g1.z*Q30;
        z1[zi] = g1.w + g0.x*S1 + g0.y*P11 + g0.z*P21 + g0.w*P31
                       + g1.x*Q11 + g1.y*Q21 + g1.z*Q31;
    }

    // ---- recon rows
    {
        const float4 db = reinterpret_cast<const float4*>(dec_b)[lane];
        float4 rec0 = db, rec1 = db;
#pragma unroll
        for (int zi = 0; zi < 8; ++zi) {
            const float4 dw = reinterpret_cast<const float4*>(dec_w)[zi * 64 + lane];
            rec0.x += z0[zi]*dw.x; rec0.y += z0[zi]*dw.y; rec0.z += z0[zi]*dw.z; rec0.w += z0[zi]*dw.w;
            rec1.x += z1[zi]*dw.x; rec1.y += z1[zi]*dw.y; rec1.z += z1[zi]*dw.z; rec1.w += z1[zi]*dw.w;
        }
        reinterpret_cast<float4*>(out_recon)[(size_t)r0 * 64 + lane] = rec0;
        reinterpret_cast<float4*>(out_recon)[(size_t)(r0+1) * 64 + lane] = rec1;
    }

    // ---- act stats: lanes 0-15 (zi=lane&7, rr=lane>>3); static select of z
    if (lane < 16) {
        const int zi = lane & 7;
        const int rr = lane >> 3;
        float zl = 0.f;
#pragma unroll
        for (int p = 0; p < 8; ++p)
            zl = (zi == p) ? (rr ? z1[p] : z0[p]) : zl;
        const float a = 1.0f / (1.0f + __expf(-zl));
        float sd = fabsf(a - 0.05f);
        sd += __shfl_xor(sd, 1); sd += __shfl_xor(sd, 2); sd += __shfl_xor(sd, 4);
        if (zi == 0) out_sdev[r0 + rr] = sd * 0.125f;
        const float rho = a + __shfl_xor(a, 8);     // row0+row1 per zi
        if (lane < 8) ws_rho[((size_t)(blockIdx.x << 2) + wave) * 8 + lane] = rho;
    }

    // ---- GAT h (lanes 0-31) and e (lanes 32-39): se terms inline
    if (lane < 32) {
        const float* gw = (lane >> 4) ? g1w : g0w;
        const int dd = lane & 15;
        float gwz[16];
#pragma unroll
        for (int f = 0; f < 16; ++f) gwz[f] = gw[f * 16 + dd];
        float h0 = 0.f, h1 = 0.f;
#pragma unroll
        for (int f = 0; f < 8; ++f) { h0 += z0[f] * gwz[f]; h1 += z1[f] * gwz[f]; }
#pragma unroll
        for (int f = 0; f < 8; ++f) {
            h0 += se[n0 * 8 + f] * gwz[8 + f];
            h1 += se[n1 * 8 + f] * gwz[8 + f];
        }
        ws_h[(size_t)r0 * 32 + lane] = h0;
        ws_h[(size_t)(r0+1) * 32 + lane] = h1;
    } else if (lane < 40) {
        const int q = (lane - 32) & 3;          // src0,dst0,src1,dst1
        const int rr = (lane - 32) >> 2;
        const int nn = rr ? n1 : n0;
        float v = 0.f;
#pragma unroll
        for (int f = 0; f < 8; ++f) v += se[nn * 8 + f] * ws_gA[q * 8 + f];
#pragma unroll
        for (int f = 0; f < 8; ++f) v += (rr ? z1[f] : z0[f]) * ws_gsz[q * 8 + f];
        ws_e[(size_t)(r0 + rr) * 4 + q] = v;
    }
}

// ---------------------------------------------------------------------------
// Kernel D: sparse GAT aggregation (lane-parallel softmax) + proj(ELU) + head
// half-wave (32 lanes) per (b,i) row; 8 rows per 256-thread block.
// Block 0 / wave 0 additionally reduces rho partials -> KL scalar.
// ---------------------------------------------------------------------------
__global__ __launch_bounds__(256) void kD(
    const float* __restrict__ ws_h, const float* __restrict__ ws_e,
    const int* __restrict__ adj,
    const float* __restrict__ proj_w, const float* __restrict__ proj_b,
    const float* __restrict__ head_w, const float* __restrict__ head_b,
    float* __restrict__ out_pred,
    const float* __restrict__ ws_rho, float* __restrict__ out_kl)
{
    const int lane = threadIdx.x & 63;
    const int wave = threadIdx.x >> 6;
    const int half = lane >> 5;
    const int t32 = lane & 31;                // phase1: neighbor slot; phase2: channel d
    const int ri = (wave << 1) + half;
    const int r = (blockIdx.x << 3) + ri;     // (b,i) row
    const int b = r >> 9;
    const int i = r & (N_ - 1);
    const int cnt = adj[i * 24];

    // own-row attention terms (esrc_h0, edst_h0, esrc_h1, edst_h1)
    const float4 er = reinterpret_cast<const float4*>(ws_e)[r];

    // ---- phase 1: lane t owns neighbor t (cnt <= 21)
    const int j = (t32 < cnt) ? adj[i * 24 + 1 + t32] : i;
    const int rj = (b << 9) | j;
    const float4 ejv = reinterpret_cast<const float4*>(ws_e)[rj];
    float e0 = er.x + ejv.y;  e0 = (e0 >= 0.f) ? e0 : 0.2f * e0;
    float e1 = er.z + ejv.w;  e1 = (e1 >= 0.f) ? e1 : 0.2f * e1;
    if (t32 >= cnt) { e0 = -3.4e38f; e1 = -3.4e38f; }
    float m0 = e0, m1 = e1;
#pragma unroll
    for (int m = 16; m >= 1; m >>= 1) {
        m0 = fmaxf(m0, __shfl_xor(m0, m));
        m1 = fmaxf(m1, __shfl_xor(m1, m));
    }
    float w0 = (t32 < cnt) ? __expf(e0 - m0) : 0.f;
    float w1 = (t32 < cnt) ? __expf(e1 - m1) : 0.f;
    float s0 = w0, s1 = w1;
#pragma unroll
    for (int m = 16; m >= 1; m >>= 1) {
        s0 += __shfl_xor(s0, m);
        s1 += __shfl_xor(s1, m);
    }

    // ---- phase 2: channel d = t32; gather h with independent (unrolled) loads.
    // Both weight shuffles execute CONVERGENTLY, then per-lane select (head-
    // divergent shuffle is UB: ds_bpermute from exec-masked-off lane).
    const int d = t32;
    const int head = d >> 4;
    const float sinv = 1.0f / (head ? s1 : s0);
    float acc = 0.f;
#pragma unroll
    for (int t = 0; t < 21; ++t) {
        const float wt0 = __shfl(w0, t, 32);
        const float wt1 = __shfl(w1, t, 32);
        const int   jt  = __shfl(j, t, 32);
        const float wt  = head ? wt1 : wt0;
        acc += wt * ws_h[(size_t)((b << 9) | jt) * 32 + d];
    }
    const float hval = acc * sinv;   // fused GAT output channel d of row r

    // ---- proj + ELU + head (all-to-all via shuffles within the 32-half)
    float f = proj_b[d];
#pragma unroll
    for (int dd = 0; dd < 32; ++dd) {
        const float hv = __shfl(hval, dd, 32);
        f += hv * proj_w[dd * 32 + d];
    }
    f = (f > 0.f) ? f : expm1f(f);
    float p = f * head_w[d];
#pragma unroll
    for (int mm = 16; mm >= 1; mm >>= 1) p += __shfl_xor(p, mm);
    if (d == 0) out_pred[r] = p + head_b[0];

    // ---- KL tail: block 0, wave 0 only (full wave active -> shuffles safe)
    if (blockIdx.x == 0 && threadIdx.x < 64) {
        float t[8] = {0, 0, 0, 0, 0, 0, 0, 0};
        for (int q = (int)threadIdx.x; q < RHOG; q += 64) {
            const float4 a = reinterpret_cast<const float4*>(ws_rho)[q * 2];
            const float4 bb = reinterpret_cast<const float4*>(ws_rho)[q * 2 + 1];
            t[0] += a.x;  t[1] += a.y;  t[2] += a.z;  t[3] += a.w;
            t[4] += bb.x; t[5] += bb.y; t[6] += bb.z; t[7] += bb.w;
        }
#pragma unroll
        for (int zi = 0; zi < 8; ++zi) t[zi] = wave_reduce_sum64(t[zi]);
        if (threadIdx.x == 0) {
            float kl = 0.f;
#pragma unroll
            for (int zi = 0; zi < 8; ++zi) {
                float rh = t[zi] * (1.0f / (float)BN_);
                rh = fminf(fmaxf(rh, 1e-6f), 1.0f - 1e-6f);
                kl += 0.05f * logf(0.05f / rh) + 0.95f * logf(0.95f / (1.0f - rh));
            }
            out_kl[0] = kl;
        }
    }
}

// ---------------------------------------------------------------------------
extern "C" void kernel_launch(void* const* d_in, const int* in_sizes, int n_in,
                              void* d_out, int out_size, void* d_ws, size_t ws_size,
                              hipStream_t stream)
{
    (void)in_sizes; (void)n_in; (void)out_size; (void)ws_size;
    const float* x     = (const float*)d_in[0];
    const float* w2    = (const float*)d_in[1];
    const float* b2    = (const float*)d_in[2];
    const float* w3    = (const float*)d_in[3];
    const float* b3    = (const float*)d_in[4];
    const float* w5    = (const float*)d_in[5];
    const float* b5    = (const float*)d_in[6];
    const float* w7    = (const float*)d_in[7];
    const float* b7    = (const float*)d_in[8];
    const float* enc_w = (const float*)d_in[9];
    const float* enc_b = (const float*)d_in[10];
    const float* dec_w = (const float*)d_in[11];
    const float* dec_b = (const float*)d_in[12];
    const float* se    = (const float*)d_in[13];
    const float* g0w   = (const float*)d_in[14];
    const float* g0s   = (const float*)d_in[15];
    const float* g0d   = (const float*)d_in[16];
    const float* g1w   = (const float*)d_in[17];
    const float* g1s   = (const float*)d_in[18];
    const float* g1d   = (const float*)d_in[19];
    const float* pw    = (const float*)d_in[20];
    const float* pb    = (const float*)d_in[21];
    const float* hw    = (const float*)d_in[22];
    const float* hb    = (const float*)d_in[23];

    float* out       = (float*)d_out;
    float* out_pred  = out;                          // 16384
    float* out_recon = out + 16384;                  // 4194304
    float* out_kl    = out + 16384 + 4194304;        // 1
    float* out_sdev  = out_kl + 1;                   // 16384

    float* ws_h   = (float*)d_ws;                         // BN_*32
    float* ws_e   = ws_h   + (size_t)BN_ * 32;            // BN_*4
    float* ws_rho = ws_e   + (size_t)BN_ * 4;             // RHOG*8
    float* ws_gam = ws_rho + (size_t)RHOG * 8;            // 64
    float* ws_gsz = ws_gam + 64;                          // 32
    float* ws_gA  = ws_gsz + 32;                          // 32
    int*   ws_adj = (int*)(ws_gA + 32);                   // N_*24 ints

    hipLaunchKernelGGL(kC2, dim3(N_ + 1), dim3(256), 0, stream,
                       se, w2, b2, w3, b3, w5, b5, w7, b7, enc_w, enc_b,
                       g0w, g0s, g0d, g1w, g1s, g1d,
                       ws_adj, ws_gam, ws_gsz, ws_gA);
    hipLaunchKernelGGL(kA, dim3(NBLK_A), dim3(256), 0, stream,
                       x, dec_w, dec_b, g0w, g1w, se,
                       ws_gam, ws_gsz, ws_gA,
                       out_recon, out_sdev, ws_h, ws_e, ws_rho);
    hipLaunchKernelGGL(kD, dim3(BN_ / 8), dim3(256), 0, stream,
                       ws_h, ws_e, ws_adj, pw, pb, hw, hb, out_pred,
                       ws_rho, out_kl);
}

// Round 8
// 54.808 us; speedup vs baseline: 1.9950x; 1.4965x over previous
//
#include <hip/hip_runtime.h>
#include <math.h>

#define B_   32
#define N_   512
#define W_   256
#define BN_  (B_*N_)        // 16384
#define NBLK_A 2048         // kA: 8 rows/block (4 waves x 2 rows)
#define RHOG   2048         // rho partial groups (one per kA BLOCK)

__device__ __forceinline__ float wave_reduce_sum64(float v) {
#pragma unroll
    for (int m = 32; m >= 1; m >>= 1) v += __shfl_xor(v, m);
    return v;
}

// ---------------------------------------------------------------------------
// Kernel C2: blocks [0,512): rank-based top-20 adjacency, one block per row.
//            block 512: tiny setup (Gamma/beta affine-z, gsz, gA).
// ---------------------------------------------------------------------------
__global__ __launch_bounds__(256) void kC2(
    const float* __restrict__ se,
    const float* __restrict__ w2, const float* __restrict__ b2,
    const float* __restrict__ w3, const float* __restrict__ b3,
    const float* __restrict__ w5, const float* __restrict__ b5,
    const float* __restrict__ w7, const float* __restrict__ b7,
    const float* __restrict__ enc_w, const float* __restrict__ enc_b,
    const float* __restrict__ g0w, const float* __restrict__ g0s, const float* __restrict__ g0d,
    const float* __restrict__ g1w, const float* __restrict__ g1s, const float* __restrict__ g1d,
    int* __restrict__ adj, float* __restrict__ ws_gam, float* __restrict__ ws_gsz,
    float* __restrict__ ws_gA)
{
    __shared__ float en[N_][9];     // padded: conflict-free
    __shared__ float sim[N_];
    __shared__ int   wc[8];

    const int tid = threadIdx.x;

    if (blockIdx.x == N_) {
        // ===================== setup block =====================
        if (tid < 64) {
            // Gamma[zi][t] (t=0..6 <-> S,P1,P2,P3,Q1,Q2,Q3), [zi][7] = beta[zi]
            const int zi = tid & 7, t = tid >> 3;
            float acc = (t == 7) ? enc_b[zi] : 0.f;
#define GAM_KI(KI, KK, CW, CB)                                                  \
            {                                                                   \
                const int k = KK; const int pl = (k - 1) >> 1;                  \
                _Pragma("unroll")                                               \
                for (int ch = 0; ch < 16; ++ch) {                               \
                    const int c = KI * 16 + ch; float a;                        \
                    if (t == 7) a = CB[ch];                                     \
                    else if (t == 0) {                                          \
                        a = 0.f;                                                \
                        _Pragma("unroll")                                       \
                        for (int j = 0; j < k; ++j) a += CW[ch*k+j];            \
                        a *= (1.f/(float)W_);                                   \
                    } else if (t <= 3) {                                        \
                        const int j = pl + t;                                   \
                        a = (j < k) ? -CW[ch*k+j]*(1.f/(float)W_) : 0.f;        \
                    } else {                                                    \
                        const int j = pl - (t - 3);                             \
                        a = (j >= 0) ? -CW[ch*k+j]*(1.f/(float)W_) : 0.f;       \
                    }                                                           \
                    acc += a * enc_w[c*8+zi];                                   \
                }                                                               \
            }
            GAM_KI(0, 2, w2, b2)
            GAM_KI(1, 3, w3, b3)
            GAM_KI(2, 5, w5, b5)
            GAM_KI(3, 7, w7, b7)
#undef GAM_KI
            ws_gam[zi*8+t] = acc;
        } else if (tid < 96) {
            // gsz[q][f] = (W_q @ a_q)[f], f<8 (z rows); q = src0,dst0,src1,dst1
            const int q = (tid-64) >> 3, f = (tid-64) & 7;
            const float* gw = (q >> 1) ? g1w : g0w;
            const float* av = (q >> 1) ? ((q&1) ? g1d : g1s) : ((q&1) ? g0d : g0s);
            float v = 0.f;
#pragma unroll
            for (int d = 0; d < 16; ++d) v += gw[f*16+d] * av[d];
            ws_gsz[q*8+f] = v;
        } else if (tid < 128) {
            // gA[q][f] = (W_q @ a_q)[8+f] (se rows)
            const int q = (tid-96) >> 3, f = (tid-96) & 7;
            const float* gw = (q >> 1) ? g1w : g0w;
            const float* av = (q >> 1) ? ((q&1) ? g1d : g1s) : ((q&1) ? g0d : g0s);
            float v = 0.f;
#pragma unroll
            for (int d = 0; d < 16; ++d) v += gw[(8+f)*16+d] * av[d];
            ws_gA[q*8+f] = v;
        }
        return;
    }

    // ================== rank block: one row i per block ==================
    const int i = blockIdx.x;

    // normalize all 512 rows cooperatively (2 rows/thread)
#pragma unroll
    for (int p = 0; p < 2; ++p) {
        const int rr = tid + p * 256;
        float v[8]; float ss = 0.f;
#pragma unroll
        for (int e = 0; e < 8; ++e) { v[e] = se[rr*8+e]; ss += v[e]*v[e]; }
        const float inv = 1.0f / fmaxf(sqrtf(ss), 1e-12f);
#pragma unroll
        for (int e = 0; e < 8; ++e) en[rr][e] = v[e] * inv;
    }
    __syncthreads();

    // sim row (2 cols/thread)
    float ei[8];
#pragma unroll
    for (int e = 0; e < 8; ++e) ei[e] = en[i][e];
    const int j0 = tid, j1 = tid + 256;
    float s0 = 0.f, s1 = 0.f;
#pragma unroll
    for (int e = 0; e < 8; ++e) { s0 += ei[e]*en[j0][e]; s1 += ei[e]*en[j1][e]; }
    s0 *= 0.35355339059327373f;   // 1/sqrt(8)
    s1 *= 0.35355339059327373f;
    if (j0 == i) s0 = -3.4e38f;
    if (j1 == i) s1 = -3.4e38f;
    sim[j0] = s0; sim[j1] = s1;
    __syncthreads();

    // rank = #{j' : sim[j'] > sim[j]  or  (== and j' < j)}; dense VALU
    int r0 = 0, r1 = 0;
    for (int q = 0; q < N_/4; ++q) {
        const float4 s4 = reinterpret_cast<const float4*>(sim)[q];
        const int jj = q * 4;
#pragma unroll
        for (int u = 0; u < 4; ++u) {
            const float sj = (u==0) ? s4.x : (u==1) ? s4.y : (u==2) ? s4.z : s4.w;
            r0 += (sj > s0 || (sj == s0 && (jj+u) < j0)) ? 1 : 0;
            r1 += (sj > s1 || (sj == s1 && (jj+u) < j1)) ? 1 : 0;
        }
    }
    const bool sel0 = (r0 < 20) && (s0 > 0.f);
    const bool sel1 = (r1 < 20) && (s1 > 0.f);

    // deterministic compaction: ballot + popcount prefix (order-stable)
    const int wave = tid >> 6, lane = tid & 63;
    const unsigned long long m0 = __ballot(sel0);
    const unsigned long long m1 = __ballot(sel1);
    if (lane == 0) { wc[wave] = __popcll(m0); wc[4+wave] = __popcll(m1); }
    __syncthreads();
    int base0 = 1, base1 = 1;   // slot 0 = self
#pragma unroll
    for (int w = 0; w < 4; ++w) base1 += wc[w];
    for (int w = 0; w < 4; ++w) {
        if (w < wave) { base0 += wc[w]; base1 += wc[4+w]; }
    }
    const unsigned long long below = (lane == 0) ? 0ull : (~0ull >> (64 - lane));
    if (sel0) adj[i*24 + 1 + base0 + __popcll(m0 & below)] = j0;
    if (sel1) adj[i*24 + 1 + base1 + __popcll(m1 & below)] = j1;
    if (tid == 0) {
        int cnt = 1;
#pragma unroll
        for (int w = 0; w < 8; ++w) cnt += wc[w];
        adj[i*24] = cnt;
        adj[i*24 + 1] = i;       // self
    }
}

// ---------------------------------------------------------------------------
// Kernel A: 2 rows/wave. z computed affinely (Gamma) by ALL lanes.
// rho partials now reduced per BLOCK (LDS + 1 barrier) -> ws_rho[2048][8].
// ---------------------------------------------------------------------------
__global__ __launch_bounds__(256) void kA(
    const float* __restrict__ x,
    const float* __restrict__ dec_w, const float* __restrict__ dec_b,
    const float* __restrict__ g0w, const float* __restrict__ g1w,
    const float* __restrict__ se,
    const float* __restrict__ ws_gam, const float* __restrict__ ws_gsz,
    const float* __restrict__ ws_gA,
    float* __restrict__ out_recon, float* __restrict__ out_sdev,
    float* __restrict__ ws_h, float* __restrict__ ws_e, float* __restrict__ ws_rho)
{
    __shared__ float lds_rho[4][8];
    const int wave = threadIdx.x >> 6;
    const int lane = threadIdx.x & 63;
    const int r0 = (blockIdx.x << 3) + (wave << 1);
    const int n0 = r0 & (N_ - 1), n1 = (r0 + 1) & (N_ - 1);

    // ---- row loads
    const float4 xv0 = reinterpret_cast<const float4*>(x)[(size_t)r0 * 64 + lane];
    const float4 xv1 = reinterpret_cast<const float4*>(x)[(size_t)(r0+1) * 64 + lane];
    const float4 ph0 = reinterpret_cast<const float4*>(x)[(size_t)r0 * 64];
    const float4 pt0 = reinterpret_cast<const float4*>(x)[(size_t)r0 * 64 + 63];
    const float4 ph1 = reinterpret_cast<const float4*>(x)[(size_t)(r0+1) * 64];
    const float4 pt1 = reinterpret_cast<const float4*>(x)[(size_t)(r0+1) * 64 + 63];

    float S0 = xv0.x + xv0.y + xv0.z + xv0.w;
    float S1 = xv1.x + xv1.y + xv1.z + xv1.w;
#pragma unroll
    for (int m = 32; m >= 1; m >>= 1) { S0 += __shfl_xor(S0, m); S1 += __shfl_xor(S1, m); }

    const float P10 = ph0.x, P20 = P10 + ph0.y, P30 = P20 + ph0.z;
    const float Q10 = pt0.w, Q20 = Q10 + pt0.z, Q30 = Q20 + pt0.y;
    const float P11 = ph1.x, P21 = P11 + ph1.y, P31 = P21 + ph1.z;
    const float Q11 = pt1.w, Q21 = Q11 + pt1.z, Q31 = Q21 + pt1.y;

    // ---- z: all lanes, affine in u (Gamma is L1-hot: 64 floats)
    float z0[8], z1[8];
#pragma unroll
    for (int zi = 0; zi < 8; ++zi) {
        const float4 g0 = reinterpret_cast<const float4*>(ws_gam)[zi * 2];
        const float4 g1 = reinterpret_cast<const float4*>(ws_gam)[zi * 2 + 1];
        z0[zi] = g1.w + g0.x*S0 + g0.y*P10 + g0.z*P20 + g0.w*P30
                       + g1.x*Q10 + g1.y*Q20 + g1.z*Q30;
        z1[zi] = g1.w + g0.x*S1 + g0.y*P11 + g0.z*P21 + g0.w*P31
                       + g1.x*Q11 + g1.y*Q21 + g1.z*Q31;
    }

    // ---- recon rows
    {
        const float4 db = reinterpret_cast<const float4*>(dec_b)[lane];
        float4 rec0 = db, rec1 = db;
#pragma unroll
        for (int zi = 0; zi < 8; ++zi) {
            const float4 dw = reinterpret_cast<const float4*>(dec_w)[zi * 64 + lane];
            rec0.x += z0[zi]*dw.x; rec0.y += z0[zi]*dw.y; rec0.z += z0[zi]*dw.z; rec0.w += z0[zi]*dw.w;
            rec1.x += z1[zi]*dw.x; rec1.y += z1[zi]*dw.y; rec1.z += z1[zi]*dw.z; rec1.w += z1[zi]*dw.w;
        }
        reinterpret_cast<float4*>(out_recon)[(size_t)r0 * 64 + lane] = rec0;
        reinterpret_cast<float4*>(out_recon)[(size_t)(r0+1) * 64 + lane] = rec1;
    }

    // ---- act stats: lanes 0-15 (zi=lane&7, rr=lane>>3); static select of z
    if (lane < 16) {
        const int zi = lane & 7;
        const int rr = lane >> 3;
        float zl = 0.f;
#pragma unroll
        for (int p = 0; p < 8; ++p)
            zl = (zi == p) ? (rr ? z1[p] : z0[p]) : zl;
        const float a = 1.0f / (1.0f + __expf(-zl));
        float sd = fabsf(a - 0.05f);
        sd += __shfl_xor(sd, 1); sd += __shfl_xor(sd, 2); sd += __shfl_xor(sd, 4);
        if (zi == 0) out_sdev[r0 + rr] = sd * 0.125f;
        const float rho = a + __shfl_xor(a, 8);     // row0+row1 per zi
        if (lane < 8) lds_rho[wave][lane] = rho;
    }

    // ---- GAT h (lanes 0-31) and e (lanes 32-39): se terms inline
    if (lane < 32) {
        const float* gw = (lane >> 4) ? g1w : g0w;
        const int dd = lane & 15;
        float gwz[16];
#pragma unroll
        for (int f = 0; f < 16; ++f) gwz[f] = gw[f * 16 + dd];
        float h0 = 0.f, h1 = 0.f;
#pragma unroll
        for (int f = 0; f < 8; ++f) { h0 += z0[f] * gwz[f]; h1 += z1[f] * gwz[f]; }
#pragma unroll
        for (int f = 0; f < 8; ++f) {
            h0 += se[n0 * 8 + f] * gwz[8 + f];
            h1 += se[n1 * 8 + f] * gwz[8 + f];
        }
        ws_h[(size_t)r0 * 32 + lane] = h0;
        ws_h[(size_t)(r0+1) * 32 + lane] = h1;
    } else if (lane < 40) {
        const int q = (lane - 32) & 3;          // src0,dst0,src1,dst1
        const int rr = (lane - 32) >> 2;
        const int nn = rr ? n1 : n0;
        float v = 0.f;
#pragma unroll
        for (int f = 0; f < 8; ++f) v += se[nn * 8 + f] * ws_gA[q * 8 + f];
#pragma unroll
        for (int f = 0; f < 8; ++f) v += (rr ? z1[f] : z0[f]) * ws_gsz[q * 8 + f];
        ws_e[(size_t)(r0 + rr) * 4 + q] = v;
    }

    // ---- block-level rho reduction: 4 waves -> 1 group of 8
    __syncthreads();
    if (threadIdx.x < 8) {
        const float t = lds_rho[0][threadIdx.x] + lds_rho[1][threadIdx.x]
                      + lds_rho[2][threadIdx.x] + lds_rho[3][threadIdx.x];
        ws_rho[(size_t)blockIdx.x * 8 + threadIdx.x] = t;
    }
}

// ---------------------------------------------------------------------------
// Kernel D: sparse GAT aggregation (lane-parallel softmax) + proj(ELU) + head
// half-wave (32 lanes) per (b,i) row; 8 rows per 256-thread block.
// Block 0 reduces rho partials -> KL with ALL 256 threads (was: 1 wave
// scanning 256 KB serially — the 50 µs straggler).
// ---------------------------------------------------------------------------
__global__ __launch_bounds__(256) void kD(
    const float* __restrict__ ws_h, const float* __restrict__ ws_e,
    const int* __restrict__ adj,
    const float* __restrict__ proj_w, const float* __restrict__ proj_b,
    const float* __restrict__ head_w, const float* __restrict__ head_b,
    float* __restrict__ out_pred,
    const float* __restrict__ ws_rho, float* __restrict__ out_kl)
{
    __shared__ float red[4][8];
    const int lane = threadIdx.x & 63;
    const int wave = threadIdx.x >> 6;
    const int half = lane >> 5;
    const int t32 = lane & 31;                // phase1: neighbor slot; phase2: channel d
    const int ri = (wave << 1) + half;
    const int r = (blockIdx.x << 3) + ri;     // (b,i) row
    const int b = r >> 9;
    const int i = r & (N_ - 1);
    const int cnt = adj[i * 24];

    // own-row attention terms (esrc_h0, edst_h0, esrc_h1, edst_h1)
    const float4 er = reinterpret_cast<const float4*>(ws_e)[r];

    // ---- phase 1: lane t owns neighbor t (cnt <= 21)
    const int j = (t32 < cnt) ? adj[i * 24 + 1 + t32] : i;
    const int rj = (b << 9) | j;
    const float4 ejv = reinterpret_cast<const float4*>(ws_e)[rj];
    float e0 = er.x + ejv.y;  e0 = (e0 >= 0.f) ? e0 : 0.2f * e0;
    float e1 = er.z + ejv.w;  e1 = (e1 >= 0.f) ? e1 : 0.2f * e1;
    if (t32 >= cnt) { e0 = -3.4e38f; e1 = -3.4e38f; }
    float m0 = e0, m1 = e1;
#pragma unroll
    for (int m = 16; m >= 1; m >>= 1) {
        m0 = fmaxf(m0, __shfl_xor(m0, m));
        m1 = fmaxf(m1, __shfl_xor(m1, m));
    }
    float w0 = (t32 < cnt) ? __expf(e0 - m0) : 0.f;
    float w1 = (t32 < cnt) ? __expf(e1 - m1) : 0.f;
    float s0 = w0, s1 = w1;
#pragma unroll
    for (int m = 16; m >= 1; m >>= 1) {
        s0 += __shfl_xor(s0, m);
        s1 += __shfl_xor(s1, m);
    }

    // ---- phase 2: channel d = t32; gather h with independent (unrolled) loads.
    // Both weight shuffles execute CONVERGENTLY, then per-lane select (head-
    // divergent shuffle is UB: ds_bpermute from exec-masked-off lane).
    const int d = t32;
    const int head = d >> 4;
    const float sinv = 1.0f / (head ? s1 : s0);
    float acc = 0.f;
#pragma unroll
    for (int t = 0; t < 21; ++t) {
        const float wt0 = __shfl(w0, t, 32);
        const float wt1 = __shfl(w1, t, 32);
        const int   jt  = __shfl(j, t, 32);
        const float wt  = head ? wt1 : wt0;
        acc += wt * ws_h[(size_t)((b << 9) | jt) * 32 + d];
    }
    const float hval = acc * sinv;   // fused GAT output channel d of row r

    // ---- proj + ELU + head (all-to-all via shuffles within the 32-half)
    float f = proj_b[d];
#pragma unroll
    for (int dd = 0; dd < 32; ++dd) {
        const float hv = __shfl(hval, dd, 32);
        f += hv * proj_w[dd * 32 + d];
    }
    f = (f > 0.f) ? f : expm1f(f);
    float p = f * head_w[d];
#pragma unroll
    for (int mm = 16; mm >= 1; mm >>= 1) p += __shfl_xor(p, mm);
    if (d == 0) out_pred[r] = p + head_b[0];

    // ---- KL tail: block 0, ALL 256 threads (8 coalesced iterations each)
    if (blockIdx.x == 0) {
        float t8[8] = {0, 0, 0, 0, 0, 0, 0, 0};
        for (int g = (int)threadIdx.x; g < RHOG; g += 256) {
            const float4 a  = reinterpret_cast<const float4*>(ws_rho)[g * 2];
            const float4 bb = reinterpret_cast<const float4*>(ws_rho)[g * 2 + 1];
            t8[0] += a.x;  t8[1] += a.y;  t8[2] += a.z;  t8[3] += a.w;
            t8[4] += bb.x; t8[5] += bb.y; t8[6] += bb.z; t8[7] += bb.w;
        }
#pragma unroll
        for (int m = 32; m >= 1; m >>= 1)
#pragma unroll
            for (int zi = 0; zi < 8; ++zi) t8[zi] += __shfl_xor(t8[zi], m);
        if (lane == 0) {
#pragma unroll
            for (int zi = 0; zi < 8; ++zi) red[wave][zi] = t8[zi];
        }
        __syncthreads();
        if (threadIdx.x == 0) {
            float kl = 0.f;
#pragma unroll
            for (int zi = 0; zi < 8; ++zi) {
                float rh = (red[0][zi] + red[1][zi] + red[2][zi] + red[3][zi])
                           * (1.0f / (float)BN_);
                rh = fminf(fmaxf(rh, 1e-6f), 1.0f - 1e-6f);
                kl += 0.05f * logf(0.05f / rh) + 0.95f * logf(0.95f / (1.0f - rh));
            }
            out_kl[0] = kl;
        }
    }
}

// ---------------------------------------------------------------------------
extern "C" void kernel_launch(void* const* d_in, const int* in_sizes, int n_in,
                              void* d_out, int out_size, void* d_ws, size_t ws_size,
                              hipStream_t stream)
{
    (void)in_sizes; (void)n_in; (void)out_size; (void)ws_size;
    const float* x     = (const float*)d_in[0];
    const float* w2    = (const float*)d_in[1];
    const float* b2    = (const float*)d_in[2];
    const float* w3    = (const float*)d_in[3];
    const float* b3    = (const float*)d_in[4];
    const float* w5    = (const float*)d_in[5];
    const float* b5    = (const float*)d_in[6];
    const float* w7    = (const float*)d_in[7];
    const float* b7    = (const float*)d_in[8];
    const float* enc_w = (const float*)d_in[9];
    const float* enc_b = (const float*)d_in[10];
    const float* dec_w = (const float*)d_in[11];
    const float* dec_b = (const float*)d_in[12];
    const float* se    = (const float*)d_in[13];
    const float* g0w   = (const float*)d_in[14];
    const float* g0s   = (const float*)d_in[15];
    const float* g0d   = (const float*)d_in[16];
    const float* g1w   = (const float*)d_in[17];
    const float* g1s   = (const float*)d_in[18];
    const float* g1d   = (const float*)d_in[19];
    const float* pw    = (const float*)d_in[20];
    const float* pb    = (const float*)d_in[21];
    const float* hw    = (const float*)d_in[22];
    const float* hb    = (const float*)d_in[23];

    float* out       = (float*)d_out;
    float* out_pred  = out;                          // 16384
    float* out_recon = out + 16384;                  // 4194304
    float* out_kl    = out + 16384 + 4194304;        // 1
    float* out_sdev  = out_kl + 1;                   // 16384

    float* ws_h   = (float*)d_ws;                         // BN_*32
    float* ws_e   = ws_h   + (size_t)BN_ * 32;            // BN_*4
    float* ws_rho = ws_e   + (size_t)BN_ * 4;             // RHOG*8
    float* ws_gam = ws_rho + (size_t)RHOG * 8;            // 64
    float* ws_gsz = ws_gam + 64;                          // 32
    float* ws_gA  = ws_gsz + 32;                          // 32
    int*   ws_adj = (int*)(ws_gA + 32);                   // N_*24 ints

    hipLaunchKernelGGL(kC2, dim3(N_ + 1), dim3(256), 0, stream,
                       se, w2, b2, w3, b3, w5, b5, w7, b7, enc_w, enc_b,
                       g0w, g0s, g0d, g1w, g1s, g1d,
                       ws_adj, ws_gam, ws_gsz, ws_gA);
    hipLaunchKernelGGL(kA, dim3(NBLK_A), dim3(256), 0, stream,
                       x, dec_w, dec_b, g0w, g1w, se,
                       ws_gam, ws_gsz, ws_gA,
                       out_recon, out_sdev, ws_h, ws_e, ws_rho);
    hipLaunchKernelGGL(kD, dim3(BN_ / 8), dim3(256), 0, stream,
                       ws_h, ws_e, ws_adj, pw, pb, hw, hb, out_pred,
                       ws_rho, out_kl);
}